// Round 18
// baseline (63.578 us; speedup 1.0000x reference)
//
#include <hip/hip_runtime.h>

#define B_ 8
#define T_ 2048
#define C_ 768
#define H_ 64
#define QT_ (T_ / 64)   // 32 Q-tiles
#define NCH_ 8          // chunks per Q-tile (chsz = 4)

typedef __bf16 bf16x8 __attribute__((ext_vector_type(8)));
typedef unsigned short ushort8 __attribute__((ext_vector_type(8)));
typedef float f32x4 __attribute__((ext_vector_type(4)));
typedef float f32x16 __attribute__((ext_vector_type(16)));

typedef __attribute__((address_space(1))) const void g_void;
typedef __attribute__((address_space(3))) void lds_void;

static __device__ __forceinline__ unsigned short f32_to_bf16(float f) {
  unsigned int u = __float_as_uint(f);
  u += 0x7FFFu + ((u >> 16) & 1u);
  return (unsigned short)(u >> 16);
}

static __device__ __forceinline__ float bf16_to_f32(unsigned short u) {
  return __uint_as_float(((unsigned int)u) << 16);
}

static __device__ __forceinline__ unsigned int cvtpk_bf16(float a, float b) {
  unsigned int r;
  asm("v_cvt_pk_bf16_f32 %0, %1, %2" : "=v"(r) : "v"(a), "v"(b));
  return r;
}

static __device__ __forceinline__ f32x4 mfma16(ushort8 a, ushort8 b, f32x4 c) {
  return __builtin_amdgcn_mfma_f32_16x16x32_bf16(
      __builtin_bit_cast(bf16x8, a), __builtin_bit_cast(bf16x8, b), c, 0, 0, 0);
}

static __device__ __forceinline__ f32x16 mfma32(ushort8 a, ushort8 b, f32x16 c) {
  return __builtin_amdgcn_mfma_f32_32x32x16_bf16(
      __builtin_bit_cast(bf16x8, a), __builtin_bit_cast(bf16x8, b), c, 0, 0, 0);
}

// Pack 8 fp32 P-values (S^T layout) into one PV A-fragment (verified round 7).
template <int BASE>
static __device__ __forceinline__ ushort8 packA(const f32x16& p) {
  unsigned int a1 = cvtpk_bf16(p[BASE + 0], p[BASE + 1]);
  unsigned int a2 = cvtpk_bf16(p[BASE + 2], p[BASE + 3]);
  unsigned int a3 = cvtpk_bf16(p[BASE + 4], p[BASE + 5]);
  unsigned int a4 = cvtpk_bf16(p[BASE + 6], p[BASE + 7]);
  asm("v_permlane32_swap_b32 %0, %1" : "+v"(a1), "+v"(a3));
  asm("v_permlane32_swap_b32 %0, %1" : "+v"(a2), "+v"(a4));
  uint4 w = {a1, a2, a3, a4};
  return __builtin_bit_cast(ushort8, w);
}

// ---------------- Kernel 0: W -> Wt in PRE-SWIZZLED per-K-step tiled layout ----------
__global__ void prep_w_kernel(const float* __restrict__ Wk, const float* __restrict__ Wq,
                              const float* __restrict__ Wv, unsigned short* __restrict__ Wt) {
  int g = blockIdx.x * 256 + threadIdx.x;
  if (g >= 24 * 768) return;
  int ks = g / 768, s = g - ks * 768;
  int n = s >> 2, perm = s & 3;
  int k8 = perm ^ (n & 3) ^ ((n >> 2) & 3);
  int p = n >> 6, col = n & 63;
  const float* W = (p == 0) ? Wk : (p == 1) ? Wq : Wv;
  float sc = (p == 1) ? 0.125f * 1.44269504088896f : 1.0f;
  int kbase = ks * 32 + k8 * 8;
  ushort8 v;
#pragma unroll
  for (int e = 0; e < 8; ++e) v[e] = f32_to_bf16(W[(kbase + e) * 64 + col] * sc);
  *(ushort8*)(Wt + (size_t)g * 8) = v;
}

// ---------------- Kernel 1: projections, W LDS-staged + DIRECT x fragments -----------
// grid = 512 blocks, 512 threads (8 waves). Wave (rg=w&1, ch3=w>>1) owns
// rows [rg*16,+16) x cols [ch3*48,+48). W double-buffered via global_load_lds
// (r12 structure); x A-fragments loaded straight from fp32 global into regs
// (coalesced 128B lines, L1-shared by the 4 waves on the same row group).
// ONE __syncthreads per K-step (vs two in r12 — Xl round-trip eliminated).
__global__ __launch_bounds__(512) void proj_kernel(
    const float* __restrict__ x, const unsigned short* __restrict__ Wt,
    unsigned short* __restrict__ Qf, unsigned short* __restrict__ Kf,
    unsigned short* __restrict__ Vf) {
  __shared__ unsigned short Wl[2][6144];
  const int tid = threadIdx.x;
  const int wave = tid >> 6, lane = tid & 63;
  const int lo = lane & 15, hi = lane >> 4;
  const int rg = wave & 1, ch3 = wave >> 1;
  const int row0 = blockIdx.x * 32;

  f32x4 acc[3];
#pragma unroll
  for (int t = 0; t < 3; ++t) acc[t] = (f32x4){0.f, 0.f, 0.f, 0.f};

  const float* xrow = x + (size_t)(row0 + rg * 16 + lo) * C_ + hi * 8;

  auto wstage = [&](int buf, int ks) {
    const unsigned short* base = Wt + (size_t)ks * 6144 + lane * 8;
    for (int is = wave; is < 12; is += 8)
      __builtin_amdgcn_global_load_lds((g_void*)(base + is * 512),
          (lds_void*)(&Wl[buf][is * 512]), 16, 0, 0);
  };

  float4 xa0, xa1, xb0 = {}, xb1 = {};

  wstage(0, 0);
  xa0 = *(const float4*)(xrow);
  xa1 = *(const float4*)(xrow + 4);

  for (int ks = 0; ks < 24; ++ks) {
    const int cur = ks & 1;
    asm volatile("s_waitcnt vmcnt(0)" ::: "memory");
    __syncthreads();                    // W[cur] staged; prior reads of cur^1 done
    if (ks + 1 < 24) {
      wstage(cur ^ 1, ks + 1);
      xb0 = *(const float4*)(xrow + (ks + 1) * 32);
      xb1 = *(const float4*)(xrow + (ks + 1) * 32 + 4);
    }
    unsigned int dd[4];
    dd[0] = cvtpk_bf16(xa0.x, xa0.y);
    dd[1] = cvtpk_bf16(xa0.z, xa0.w);
    dd[2] = cvtpk_bf16(xa1.x, xa1.y);
    dd[3] = cvtpk_bf16(xa1.z, xa1.w);
    ushort8 af = __builtin_bit_cast(ushort8, *(uint4*)dd);
#pragma unroll
    for (int t = 0; t < 3; ++t) {
      const int n = ch3 * 48 + t * 16 + lo;
      const int baddr = (n * 4 + (hi ^ (n & 3) ^ ((n >> 2) & 3))) * 8;
      ushort8 bfr = *(const ushort8*)(&Wl[cur][baddr]);
      acc[t] = mfma16(af, bfr, acc[t]);
    }
    xa0 = xb0;
    xa1 = xb1;
  }

  // epilogue: write Q/K/V in attn MFMA-fragment order
#pragma unroll
  for (int t = 0; t < 3; ++t) {
    const int n = ch3 * 48 + t * 16 + lo;
    const int p = n >> 6, d = n & 63;
#pragma unroll
    for (int r = 0; r < 4; ++r) {
      const int rgl = row0 + rg * 16 + hi * 4 + r;
      const int b = rgl >> 11;
      const int tt = rgl & (T_ - 1);
      unsigned short val = f32_to_bf16(acc[t][r]);
      if (p == 2) {
        const size_t addr = ((((size_t)b * 128 + (tt >> 4)) * 2 + (d >> 5)) * 64 +
                             ((tt >> 3) & 1) * 32 + (d & 31)) * 8 + (tt & 7);
        Vf[addr] = val;
      } else {
        const size_t addr = ((((size_t)b * 64 + (tt >> 5)) * 4 + (d >> 4)) * 64 +
                             ((d >> 3) & 1) * 32 + (tt & 31)) * 8 + (d & 7);
        if (p == 0) Kf[addr] = val; else Qf[addr] = val;
      }
    }
  }
}

// ---------------- Kernel 2: swapped 32x32 flash attention (round-14 exact) -----------
// 1D grid, XCD swizzle (b = id & 7). 2 independent waves, no LDS/barriers.
// Defer-max (THR=8).
__global__ __launch_bounds__(128) void attn_part_kernel(
    const unsigned short* __restrict__ Qf, const unsigned short* __restrict__ Kf,
    const unsigned short* __restrict__ Vf, unsigned short* __restrict__ Opb,
    float* __restrict__ Ml) {
  const int id = blockIdx.x;
  const int b = id & 7;
  const int r2 = id >> 3;
  const int qt = r2 & 31;
  const int ch = r2 >> 5;
  const int t0 = ch * 4;
  if (t0 > qt) return;
  const int t1 = min(qt, t0 + 3);

  const int tid = threadIdx.x;
  const int wave = tid >> 6;
  const int lane = tid & 63;
  const int il = lane & 31;
  const int h = lane >> 5;
  const int i0w = qt * 64 + wave * 32;

  const unsigned short* qbase = Qf + ((((size_t)b * 64 + (qt * 2 + wave)) * 4) << 9) + lane * 8;
  const unsigned short* kbase = Kf + (((size_t)b * 64) << 11) + lane * 8;
  const unsigned short* vbase = Vf + (((size_t)b * 128) << 10) + lane * 8;

  ushort8 qf[4];
#pragma unroll
  for (int dc = 0; dc < 4; ++dc) qf[dc] = *(const ushort8*)(qbase + (dc << 9));

  f32x16 o0 = {}, o1 = {};
  float m = -1e30f, lsum = 0.f;

  for (int jt = t0; jt <= t1; ++jt) {
    const int j0 = jt * 64;
    const size_t jg = (size_t)(jt * 2);

    ushort8 kf0[4], kf1[4];
#pragma unroll
    for (int dc = 0; dc < 4; ++dc) {
      kf0[dc] = *(const ushort8*)(kbase + (jg << 11) + (dc << 9));
      kf1[dc] = *(const ushort8*)(kbase + ((jg + 1) << 11) + (dc << 9));
    }
    ushort8 vf0[4], vf1[4];
#pragma unroll
    for (int c = 0; c < 4; ++c) {
      const size_t jc = (size_t)(jt * 4 + c);
      vf0[c] = *(const ushort8*)(vbase + (jc << 10));
      vf1[c] = *(const ushort8*)(vbase + (jc << 10) + (1 << 9));
    }

    f32x16 s0 = {}, s1 = {};
    __builtin_amdgcn_s_setprio(1);
#pragma unroll
    for (int dc = 0; dc < 4; ++dc) {
      s0 = mfma32(kf0[dc], qf[dc], s0);
      s1 = mfma32(kf1[dc], qf[dc], s1);
    }
    __builtin_amdgcn_s_setprio(0);

    if (jt == qt) {
      const int ig = i0w + il;
#pragma unroll
      for (int r = 0; r < 16; ++r) {
        const int jl = j0 + (r & 3) + 8 * (r >> 2) + 4 * h;
        if (jl > ig) s0[r] = -1e30f;
        if (jl + 32 > ig) s1[r] = -1e30f;
      }
    }

    // online softmax, tree-reduced, defer-max (THR=8)
    float mx[8];
#pragma unroll
    for (int r = 0; r < 8; ++r) mx[r] = fmaxf(fmaxf(s0[r], s0[r + 8]), fmaxf(s1[r], s1[r + 8]));
#pragma unroll
    for (int d = 4; d >= 1; d >>= 1)
#pragma unroll
      for (int r = 0; r < d; ++r) mx[r] = fmaxf(mx[r], mx[r + d]);
    float tm = fmaxf(mx[0], __shfl_xor(mx[0], 32));
    float scl = 1.0f;
    if (!__all(tm <= m + 8.0f)) {
      const float mnew = fmaxf(m, tm);
      scl = exp2f(m - mnew);
      m = mnew;
      o0 *= scl;
      o1 *= scl;
    }
    float sa = 0.f, sb = 0.f, sc2 = 0.f, sd = 0.f;
#pragma unroll
    for (int r = 0; r < 16; r += 4) {
      s0[r] = exp2f(s0[r] - m);     sa += s0[r];
      s0[r + 1] = exp2f(s0[r + 1] - m); sb += s0[r + 1];
      s0[r + 2] = exp2f(s0[r + 2] - m); sc2 += s0[r + 2];
      s0[r + 3] = exp2f(s0[r + 3] - m); sd += s0[r + 3];
    }
#pragma unroll
    for (int r = 0; r < 16; r += 4) {
      s1[r] = exp2f(s1[r] - m);     sa += s1[r];
      s1[r + 1] = exp2f(s1[r + 1] - m); sb += s1[r + 1];
      s1[r + 2] = exp2f(s1[r + 2] - m); sc2 += s1[r + 2];
      s1[r + 3] = exp2f(s1[r + 3] - m); sd += s1[r + 3];
    }
    float ts = (sa + sb) + (sc2 + sd);
    ts += __shfl_xor(ts, 32);
    lsum = lsum * scl + ts;

    __builtin_amdgcn_s_setprio(1);
#pragma unroll
    for (int c = 0; c < 4; ++c) {
      ushort8 pa = (c == 0) ? packA<0>(s0) : (c == 1) ? packA<8>(s0)
                 : (c == 2) ? packA<0>(s1) : packA<8>(s1);
      o0 = mfma32(vf0[c], pa, o0);
      o1 = mfma32(vf1[c], pa, o1);
    }
    __builtin_amdgcn_s_setprio(0);
  }

  const size_t pb = (size_t)(b * QT_ + qt) * NCH_ + ch;
  unsigned short* op = Opb + pb * 4096 + (size_t)(wave * 32 + il) * 64;
#pragma unroll
  for (int g = 0; g < 4; ++g) {
    unsigned int w0[2], w1[2];
    w0[0] = cvtpk_bf16(o0[4 * g + 0], o0[4 * g + 1]);
    w0[1] = cvtpk_bf16(o0[4 * g + 2], o0[4 * g + 3]);
    w1[0] = cvtpk_bf16(o1[4 * g + 0], o1[4 * g + 1]);
    w1[1] = cvtpk_bf16(o1[4 * g + 2], o1[4 * g + 3]);
    *(uint2*)(op + 8 * g + 4 * h) = *(uint2*)w0;
    *(uint2*)(op + 32 + 8 * g + 4 * h) = *(uint2*)w1;
  }
  if (h == 0) {
    float* ml = Ml + pb * 128;
    ml[wave * 32 + il] = m;
    ml[64 + wave * 32 + il] = lsum;
  }
}

// ---------------- Kernel 3: combine split-j partials (bf16, XCD-swizzled) ------------
__global__ __launch_bounds__(256) void attn_comb_kernel(
    const unsigned short* __restrict__ Opb, const float* __restrict__ Ml,
    float* __restrict__ out) {
  const int id = blockIdx.x;
  const int b = id & 7;
  const int qt = id >> 3;
  const int nc = (qt >> 2) + 1;
  const int row = threadIdx.x >> 2;
  const int c0 = (threadIdx.x & 3) * 16;
  const size_t pbase = (size_t)(b * QT_ + qt) * NCH_;

  float m_g = -1e30f;
  for (int c = 0; c < nc; ++c) m_g = fmaxf(m_g, Ml[(pbase + c) * 128 + row]);
  float l_g = 0.f;
  for (int c = 0; c < nc; ++c)
    l_g += Ml[(pbase + c) * 128 + 64 + row] * exp2f(Ml[(pbase + c) * 128 + row] - m_g);
  const float inv = 1.0f / l_g;

  f32x4 a0 = {0,0,0,0}, a1 = {0,0,0,0}, a2 = {0,0,0,0}, a3 = {0,0,0,0};
  for (int c = 0; c < nc; ++c) {
    const float wc = exp2f(Ml[(pbase + c) * 128 + row] - m_g);
    const unsigned short* op = Opb + (pbase + c) * 4096 + row * 64 + c0;
    ushort8 u0 = *(const ushort8*)(op);
    ushort8 u1 = *(const ushort8*)(op + 8);
    a0 += (f32x4){bf16_to_f32(u0[0]), bf16_to_f32(u0[1]), bf16_to_f32(u0[2]), bf16_to_f32(u0[3])} * wc;
    a1 += (f32x4){bf16_to_f32(u0[4]), bf16_to_f32(u0[5]), bf16_to_f32(u0[6]), bf16_to_f32(u0[7])} * wc;
    a2 += (f32x4){bf16_to_f32(u1[0]), bf16_to_f32(u1[1]), bf16_to_f32(u1[2]), bf16_to_f32(u1[3])} * wc;
    a3 += (f32x4){bf16_to_f32(u1[4]), bf16_to_f32(u1[5]), bf16_to_f32(u1[6]), bf16_to_f32(u1[7])} * wc;
  }
  float* o = out + ((size_t)b * T_ + qt * 64 + row) * 64 + c0;
  *(f32x4*)(o) = a0 * inv;
  *(f32x4*)(o + 4) = a1 * inv;
  *(f32x4*)(o + 8) = a2 * inv;
  *(f32x4*)(o + 12) = a3 * inv;
}

extern "C" void kernel_launch(void* const* d_in, const int* in_sizes, int n_in,
                              void* d_out, int out_size, void* d_ws, size_t ws_size,
                              hipStream_t stream) {
  const float* x = (const float*)d_in[0];
  const float* Wk = (const float*)d_in[1];
  const float* Wq = (const float*)d_in[2];
  const float* Wv = (const float*)d_in[3];
  float* out = (float*)d_out;

  char* ws = (char*)d_ws;
  unsigned short* Qf = (unsigned short*)(ws);                  // 2 MB  fragment-order Q
  unsigned short* Kf = (unsigned short*)(ws + (2u << 20));     // 2 MB  fragment-order K
  unsigned short* Vf = (unsigned short*)(ws + (4u << 20));     // 2 MB  fragment-order V
  unsigned short* Wt = (unsigned short*)(ws + (6u << 20));     // 288 KB swizzled
  unsigned short* Opb = (unsigned short*)(ws + (8u << 20));    // 16 MB bf16 partial O
  float* Ml = (float*)(ws + (24u << 20));                      // 1 MB  [pb][2][64] f32

  prep_w_kernel<<<dim3(72), dim3(256), 0, stream>>>(Wk, Wq, Wv, Wt);
  proj_kernel<<<dim3((B_ * T_) / 32), dim3(512), 0, stream>>>(x, Wt, Qf, Kf, Vf);
  attn_part_kernel<<<dim3(QT_ * B_ * NCH_), dim3(128), 0, stream>>>(Qf, Kf, Vf, Opb, Ml);
  attn_comb_kernel<<<dim3(QT_ * B_), dim3(256), 0, stream>>>(Opb, Ml, out);
}

// Round 19
// 61.412 us; speedup vs baseline: 1.0353x; 1.0353x over previous
//
#include <hip/hip_runtime.h>

#define B_ 8
#define T_ 2048
#define C_ 768
#define H_ 64
#define QT_ (T_ / 64)   // 32 Q-tiles
#define NCH_ 16         // chunks per Q-tile (chsz = 2) — barrier-free attn retry

typedef __bf16 bf16x8 __attribute__((ext_vector_type(8)));
typedef unsigned short ushort8 __attribute__((ext_vector_type(8)));
typedef float f32x4 __attribute__((ext_vector_type(4)));
typedef float f32x16 __attribute__((ext_vector_type(16)));

typedef __attribute__((address_space(1))) const void g_void;
typedef __attribute__((address_space(3))) void lds_void;

static __device__ __forceinline__ unsigned short f32_to_bf16(float f) {
  unsigned int u = __float_as_uint(f);
  u += 0x7FFFu + ((u >> 16) & 1u);
  return (unsigned short)(u >> 16);
}

static __device__ __forceinline__ float bf16_to_f32(unsigned short u) {
  return __uint_as_float(((unsigned int)u) << 16);
}

static __device__ __forceinline__ unsigned int cvtpk_bf16(float a, float b) {
  unsigned int r;
  asm("v_cvt_pk_bf16_f32 %0, %1, %2" : "=v"(r) : "v"(a), "v"(b));
  return r;
}

static __device__ __forceinline__ f32x4 mfma16(ushort8 a, ushort8 b, f32x4 c) {
  return __builtin_amdgcn_mfma_f32_16x16x32_bf16(
      __builtin_bit_cast(bf16x8, a), __builtin_bit_cast(bf16x8, b), c, 0, 0, 0);
}

static __device__ __forceinline__ f32x16 mfma32(ushort8 a, ushort8 b, f32x16 c) {
  return __builtin_amdgcn_mfma_f32_32x32x16_bf16(
      __builtin_bit_cast(bf16x8, a), __builtin_bit_cast(bf16x8, b), c, 0, 0, 0);
}

// Pack 8 fp32 P-values (S^T layout) into one PV A-fragment (verified round 7).
template <int BASE>
static __device__ __forceinline__ ushort8 packA(const f32x16& p) {
  unsigned int a1 = cvtpk_bf16(p[BASE + 0], p[BASE + 1]);
  unsigned int a2 = cvtpk_bf16(p[BASE + 2], p[BASE + 3]);
  unsigned int a3 = cvtpk_bf16(p[BASE + 4], p[BASE + 5]);
  unsigned int a4 = cvtpk_bf16(p[BASE + 6], p[BASE + 7]);
  asm("v_permlane32_swap_b32 %0, %1" : "+v"(a1), "+v"(a3));
  asm("v_permlane32_swap_b32 %0, %1" : "+v"(a2), "+v"(a4));
  uint4 w = {a1, a2, a3, a4};
  return __builtin_bit_cast(ushort8, w);
}

// ---------------- Kernel 0: W -> Wt in PRE-SWIZZLED per-K-step tiled layout ----------
__global__ void prep_w_kernel(const float* __restrict__ Wk, const float* __restrict__ Wq,
                              const float* __restrict__ Wv, unsigned short* __restrict__ Wt) {
  int g = blockIdx.x * 256 + threadIdx.x;
  if (g >= 24 * 768) return;
  int ks = g / 768, s = g - ks * 768;
  int n = s >> 2, perm = s & 3;
  int k8 = perm ^ (n & 3) ^ ((n >> 2) & 3);
  int p = n >> 6, col = n & 63;
  const float* W = (p == 0) ? Wk : (p == 1) ? Wq : Wv;
  float sc = (p == 1) ? 0.125f * 1.44269504088896f : 1.0f;
  int kbase = ks * 32 + k8 * 8;
  ushort8 v;
#pragma unroll
  for (int e = 0; e < 8; ++e) v[e] = f32_to_bf16(W[(kbase + e) * 64 + col] * sc);
  *(ushort8*)(Wt + (size_t)g * 8) = v;
}

// ---------------- Kernel 1: projections (round-12/14 exact, best measured) -----------
__global__ __launch_bounds__(512) void proj_kernel(
    const float* __restrict__ x, const unsigned short* __restrict__ Wt,
    unsigned short* __restrict__ Qf, unsigned short* __restrict__ Kf,
    unsigned short* __restrict__ Vf) {
  __shared__ unsigned short Wl[2][6144];
  __shared__ unsigned short Xl[2][1024];
  const int tid = threadIdx.x;
  const int wave = tid >> 6, lane = tid & 63;
  const int lo = lane & 15, hi = lane >> 4;
  const int rg = wave & 1, ch3 = wave >> 1;
  const int row0 = blockIdx.x * 32;

  f32x4 acc[3];
#pragma unroll
  for (int t = 0; t < 3; ++t) acc[t] = (f32x4){0.f, 0.f, 0.f, 0.f};

  const int xr = (tid & 127) >> 2;
  const int xk8 = tid & 3;
  const int xslot = xr * 4 + (xk8 ^ (xr & 3) ^ ((xr >> 2) & 3));
  const float* xsrc = x + (size_t)(row0 + xr) * C_ + xk8 * 8;

  const int arow = rg * 16 + lo;
  const int aaddr = (arow * 4 + (hi ^ (arow & 3) ^ ((arow >> 2) & 3))) * 8;

  auto wstage = [&](int buf, int ks) {
    const unsigned short* base = Wt + (size_t)ks * 6144 + lane * 8;
    for (int is = wave; is < 12; is += 8)
      __builtin_amdgcn_global_load_lds((g_void*)(base + is * 512),
          (lds_void*)(&Wl[buf][is * 512]), 16, 0, 0);
  };

  float4 xa0 = {}, xa1 = {}, xb0 = {}, xb1 = {};

  wstage(0, 0);
  if (tid < 128) {
    xa0 = *(const float4*)(xsrc);
    xa1 = *(const float4*)(xsrc + 4);
  }

  for (int ks = 0; ks < 24; ++ks) {
    const int cur = ks & 1;
    asm volatile("s_waitcnt vmcnt(0)" ::: "memory");
    __syncthreads();
    if (ks + 1 < 24) {
      wstage(cur ^ 1, ks + 1);
      if (tid < 128) {
        xb0 = *(const float4*)(xsrc + (ks + 1) * 32);
        xb1 = *(const float4*)(xsrc + (ks + 1) * 32 + 4);
      }
    }
    if (tid < 128) {
      unsigned int dd[4];
      dd[0] = cvtpk_bf16(xa0.x, xa0.y);
      dd[1] = cvtpk_bf16(xa0.z, xa0.w);
      dd[2] = cvtpk_bf16(xa1.x, xa1.y);
      dd[3] = cvtpk_bf16(xa1.z, xa1.w);
      *(uint4*)(&Xl[cur][xslot * 8]) = *(uint4*)dd;
    }
    __syncthreads();
    ushort8 af = *(const ushort8*)(&Xl[cur][aaddr]);
#pragma unroll
    for (int t = 0; t < 3; ++t) {
      const int n = ch3 * 48 + t * 16 + lo;
      const int baddr = (n * 4 + (hi ^ (n & 3) ^ ((n >> 2) & 3))) * 8;
      ushort8 bfr = *(const ushort8*)(&Wl[cur][baddr]);
      acc[t] = mfma16(af, bfr, acc[t]);
    }
    xa0 = xb0; xa1 = xb1;
  }

#pragma unroll
  for (int t = 0; t < 3; ++t) {
    const int n = ch3 * 48 + t * 16 + lo;
    const int p = n >> 6, d = n & 63;
#pragma unroll
    for (int r = 0; r < 4; ++r) {
      const int rgl = row0 + rg * 16 + hi * 4 + r;
      const int b = rgl >> 11;
      const int tt = rgl & (T_ - 1);
      unsigned short val = f32_to_bf16(acc[t][r]);
      if (p == 2) {
        const size_t addr = ((((size_t)b * 128 + (tt >> 4)) * 2 + (d >> 5)) * 64 +
                             ((tt >> 3) & 1) * 32 + (d & 31)) * 8 + (tt & 7);
        Vf[addr] = val;
      } else {
        const size_t addr = ((((size_t)b * 64 + (tt >> 5)) * 4 + (d >> 4)) * 64 +
                             ((d >> 3) & 1) * 32 + (tt & 31)) * 8 + (d & 7);
        if (p == 0) Kf[addr] = val; else Qf[addr] = val;
      }
    }
  }
}

// ---------------- Kernel 2: swapped 32x32 flash attention, chsz=2 --------------------
// 1D grid, XCD swizzle (b = id & 7). 2 independent waves, no LDS/barriers.
// chsz=2 => 2176 active blocks = 4.25 waves/SIMD supply (2x round 14).
// Defer-max (THR=8).
__global__ __launch_bounds__(128) void attn_part_kernel(
    const unsigned short* __restrict__ Qf, const unsigned short* __restrict__ Kf,
    const unsigned short* __restrict__ Vf, unsigned short* __restrict__ Opb,
    float* __restrict__ Ml) {
  const int id = blockIdx.x;
  const int b = id & 7;
  const int r2 = id >> 3;
  const int qt = r2 & 31;
  const int ch = r2 >> 5;
  const int t0 = ch * 2;
  if (t0 > qt) return;
  const int t1 = min(qt, t0 + 1);

  const int tid = threadIdx.x;
  const int wave = tid >> 6;
  const int lane = tid & 63;
  const int il = lane & 31;
  const int h = lane >> 5;
  const int i0w = qt * 64 + wave * 32;

  const unsigned short* qbase = Qf + ((((size_t)b * 64 + (qt * 2 + wave)) * 4) << 9) + lane * 8;
  const unsigned short* kbase = Kf + (((size_t)b * 64) << 11) + lane * 8;
  const unsigned short* vbase = Vf + (((size_t)b * 128) << 10) + lane * 8;

  ushort8 qf[4];
#pragma unroll
  for (int dc = 0; dc < 4; ++dc) qf[dc] = *(const ushort8*)(qbase + (dc << 9));

  f32x16 o0 = {}, o1 = {};
  float m = -1e30f, lsum = 0.f;

  for (int jt = t0; jt <= t1; ++jt) {
    const int j0 = jt * 64;
    const size_t jg = (size_t)(jt * 2);

    ushort8 kf0[4], kf1[4];
#pragma unroll
    for (int dc = 0; dc < 4; ++dc) {
      kf0[dc] = *(const ushort8*)(kbase + (jg << 11) + (dc << 9));
      kf1[dc] = *(const ushort8*)(kbase + ((jg + 1) << 11) + (dc << 9));
    }
    ushort8 vf0[4], vf1[4];
#pragma unroll
    for (int c = 0; c < 4; ++c) {
      const size_t jc = (size_t)(jt * 4 + c);
      vf0[c] = *(const ushort8*)(vbase + (jc << 10));
      vf1[c] = *(const ushort8*)(vbase + (jc << 10) + (1 << 9));
    }

    f32x16 s0 = {}, s1 = {};
    __builtin_amdgcn_s_setprio(1);
#pragma unroll
    for (int dc = 0; dc < 4; ++dc) {
      s0 = mfma32(kf0[dc], qf[dc], s0);
      s1 = mfma32(kf1[dc], qf[dc], s1);
    }
    __builtin_amdgcn_s_setprio(0);

    if (jt == qt) {
      const int ig = i0w + il;
#pragma unroll
      for (int r = 0; r < 16; ++r) {
        const int jl = j0 + (r & 3) + 8 * (r >> 2) + 4 * h;
        if (jl > ig) s0[r] = -1e30f;
        if (jl + 32 > ig) s1[r] = -1e30f;
      }
    }

    // online softmax, tree-reduced, defer-max (THR=8)
    float mx[8];
#pragma unroll
    for (int r = 0; r < 8; ++r) mx[r] = fmaxf(fmaxf(s0[r], s0[r + 8]), fmaxf(s1[r], s1[r + 8]));
#pragma unroll
    for (int d = 4; d >= 1; d >>= 1)
#pragma unroll
      for (int r = 0; r < d; ++r) mx[r] = fmaxf(mx[r], mx[r + d]);
    float tm = fmaxf(mx[0], __shfl_xor(mx[0], 32));
    float scl = 1.0f;
    if (!__all(tm <= m + 8.0f)) {
      const float mnew = fmaxf(m, tm);
      scl = exp2f(m - mnew);
      m = mnew;
      o0 *= scl;
      o1 *= scl;
    }
    float sa = 0.f, sb = 0.f, sc2 = 0.f, sd = 0.f;
#pragma unroll
    for (int r = 0; r < 16; r += 4) {
      s0[r] = exp2f(s0[r] - m);     sa += s0[r];
      s0[r + 1] = exp2f(s0[r + 1] - m); sb += s0[r + 1];
      s0[r + 2] = exp2f(s0[r + 2] - m); sc2 += s0[r + 2];
      s0[r + 3] = exp2f(s0[r + 3] - m); sd += s0[r + 3];
    }
#pragma unroll
    for (int r = 0; r < 16; r += 4) {
      s1[r] = exp2f(s1[r] - m);     sa += s1[r];
      s1[r + 1] = exp2f(s1[r + 1] - m); sb += s1[r + 1];
      s1[r + 2] = exp2f(s1[r + 2] - m); sc2 += s1[r + 2];
      s1[r + 3] = exp2f(s1[r + 3] - m); sd += s1[r + 3];
    }
    float ts = (sa + sb) + (sc2 + sd);
    ts += __shfl_xor(ts, 32);
    lsum = lsum * scl + ts;

    __builtin_amdgcn_s_setprio(1);
#pragma unroll
    for (int c = 0; c < 4; ++c) {
      ushort8 pa = (c == 0) ? packA<0>(s0) : (c == 1) ? packA<8>(s0)
                 : (c == 2) ? packA<0>(s1) : packA<8>(s1);
      o0 = mfma32(vf0[c], pa, o0);
      o1 = mfma32(vf1[c], pa, o1);
    }
    __builtin_amdgcn_s_setprio(0);
  }

  const size_t pb = (size_t)(b * QT_ + qt) * NCH_ + ch;
  unsigned short* op = Opb + pb * 4096 + (size_t)(wave * 32 + il) * 64;
#pragma unroll
  for (int g = 0; g < 4; ++g) {
    unsigned int w0[2], w1[2];
    w0[0] = cvtpk_bf16(o0[4 * g + 0], o0[4 * g + 1]);
    w0[1] = cvtpk_bf16(o0[4 * g + 2], o0[4 * g + 3]);
    w1[0] = cvtpk_bf16(o1[4 * g + 0], o1[4 * g + 1]);
    w1[1] = cvtpk_bf16(o1[4 * g + 2], o1[4 * g + 3]);
    *(uint2*)(op + 8 * g + 4 * h) = *(uint2*)w0;
    *(uint2*)(op + 32 + 8 * g + 4 * h) = *(uint2*)w1;
  }
  if (h == 0) {
    float* ml = Ml + pb * 128;
    ml[wave * 32 + il] = m;
    ml[64 + wave * 32 + il] = lsum;
  }
}

// ---------------- Kernel 3: combine split-j partials (bf16, XCD-swizzled) ------------
__global__ __launch_bounds__(256) void attn_comb_kernel(
    const unsigned short* __restrict__ Opb, const float* __restrict__ Ml,
    float* __restrict__ out) {
  const int id = blockIdx.x;
  const int b = id & 7;
  const int qt = id >> 3;
  const int nc = (qt >> 1) + 1;
  const int row = threadIdx.x >> 2;
  const int c0 = (threadIdx.x & 3) * 16;
  const size_t pbase = (size_t)(b * QT_ + qt) * NCH_;

  float m_g = -1e30f;
  for (int c = 0; c < nc; ++c) m_g = fmaxf(m_g, Ml[(pbase + c) * 128 + row]);
  float l_g = 0.f;
  for (int c = 0; c < nc; ++c)
    l_g += Ml[(pbase + c) * 128 + 64 + row] * exp2f(Ml[(pbase + c) * 128 + row] - m_g);
  const float inv = 1.0f / l_g;

  f32x4 a0 = {0,0,0,0}, a1 = {0,0,0,0}, a2 = {0,0,0,0}, a3 = {0,0,0,0};
  for (int c = 0; c < nc; ++c) {
    const float wc = exp2f(Ml[(pbase + c) * 128 + row] - m_g);
    const unsigned short* op = Opb + (pbase + c) * 4096 + row * 64 + c0;
    ushort8 u0 = *(const ushort8*)(op);
    ushort8 u1 = *(const ushort8*)(op + 8);
    a0 += (f32x4){bf16_to_f32(u0[0]), bf16_to_f32(u0[1]), bf16_to_f32(u0[2]), bf16_to_f32(u0[3])} * wc;
    a1 += (f32x4){bf16_to_f32(u0[4]), bf16_to_f32(u0[5]), bf16_to_f32(u0[6]), bf16_to_f32(u0[7])} * wc;
    a2 += (f32x4){bf16_to_f32(u1[0]), bf16_to_f32(u1[1]), bf16_to_f32(u1[2]), bf16_to_f32(u1[3])} * wc;
    a3 += (f32x4){bf16_to_f32(u1[4]), bf16_to_f32(u1[5]), bf16_to_f32(u1[6]), bf16_to_f32(u1[7])} * wc;
  }
  float* o = out + ((size_t)b * T_ + qt * 64 + row) * 64 + c0;
  *(f32x4*)(o) = a0 * inv;
  *(f32x4*)(o + 4) = a1 * inv;
  *(f32x4*)(o + 8) = a2 * inv;
  *(f32x4*)(o + 12) = a3 * inv;
}

extern "C" void kernel_launch(void* const* d_in, const int* in_sizes, int n_in,
                              void* d_out, int out_size, void* d_ws, size_t ws_size,
                              hipStream_t stream) {
  const float* x = (const float*)d_in[0];
  const float* Wk = (const float*)d_in[1];
  const float* Wq = (const float*)d_in[2];
  const float* Wv = (const float*)d_in[3];
  float* out = (float*)d_out;

  char* ws = (char*)d_ws;
  unsigned short* Qf = (unsigned short*)(ws);                  // 2 MB  fragment-order Q
  unsigned short* Kf = (unsigned short*)(ws + (2u << 20));     // 2 MB  fragment-order K
  unsigned short* Vf = (unsigned short*)(ws + (4u << 20));     // 2 MB  fragment-order V
  unsigned short* Wt = (unsigned short*)(ws + (6u << 20));     // 288 KB swizzled
  unsigned short* Opb = (unsigned short*)(ws + (8u << 20));    // 32 MB bf16 partial O
  float* Ml = (float*)(ws + (40u << 20));                      // 2 MB  [pb][2][64] f32

  prep_w_kernel<<<dim3(72), dim3(256), 0, stream>>>(Wk, Wq, Wv, Wt);
  proj_kernel<<<dim3((B_ * T_) / 32), dim3(512), 0, stream>>>(x, Wt, Qf, Kf, Vf);
  attn_part_kernel<<<dim3(QT_ * B_ * NCH_), dim3(128), 0, stream>>>(Qf, Kf, Vf, Opb, Ml);
  attn_comb_kernel<<<dim3(QT_ * B_), dim3(256), 0, stream>>>(Opb, Ml, out);
}

// Round 20
// 54.533 us; speedup vs baseline: 1.1658x; 1.1261x over previous
//
#include <hip/hip_runtime.h>

#define B_ 8
#define T_ 2048
#define C_ 768
#define H_ 64
#define QT_ (T_ / 64)   // 32 Q-tiles
#define NCH_ 8          // chunks per Q-tile (chsz = 4)

typedef __bf16 bf16x8 __attribute__((ext_vector_type(8)));
typedef unsigned short ushort8 __attribute__((ext_vector_type(8)));
typedef float f32x4 __attribute__((ext_vector_type(4)));
typedef float f32x16 __attribute__((ext_vector_type(16)));

typedef __attribute__((address_space(1))) const void g_void;
typedef __attribute__((address_space(3))) void lds_void;

static __device__ __forceinline__ unsigned short f32_to_bf16(float f) {
  unsigned int u = __float_as_uint(f);
  u += 0x7FFFu + ((u >> 16) & 1u);
  return (unsigned short)(u >> 16);
}

static __device__ __forceinline__ float bf16_to_f32(unsigned short u) {
  return __uint_as_float(((unsigned int)u) << 16);
}

static __device__ __forceinline__ unsigned int cvtpk_bf16(float a, float b) {
  unsigned int r;
  asm("v_cvt_pk_bf16_f32 %0, %1, %2" : "=v"(r) : "v"(a), "v"(b));
  return r;
}

static __device__ __forceinline__ f32x4 mfma16(ushort8 a, ushort8 b, f32x4 c) {
  return __builtin_amdgcn_mfma_f32_16x16x32_bf16(
      __builtin_bit_cast(bf16x8, a), __builtin_bit_cast(bf16x8, b), c, 0, 0, 0);
}

static __device__ __forceinline__ f32x16 mfma32(ushort8 a, ushort8 b, f32x16 c) {
  return __builtin_amdgcn_mfma_f32_32x32x16_bf16(
      __builtin_bit_cast(bf16x8, a), __builtin_bit_cast(bf16x8, b), c, 0, 0, 0);
}

// Pack 8 fp32 P-values (S^T layout) into one PV A-fragment (verified round 7).
template <int BASE>
static __device__ __forceinline__ ushort8 packA(const f32x16& p) {
  unsigned int a1 = cvtpk_bf16(p[BASE + 0], p[BASE + 1]);
  unsigned int a2 = cvtpk_bf16(p[BASE + 2], p[BASE + 3]);
  unsigned int a3 = cvtpk_bf16(p[BASE + 4], p[BASE + 5]);
  unsigned int a4 = cvtpk_bf16(p[BASE + 6], p[BASE + 7]);
  asm("v_permlane32_swap_b32 %0, %1" : "+v"(a1), "+v"(a3));
  asm("v_permlane32_swap_b32 %0, %1" : "+v"(a2), "+v"(a4));
  uint4 w = {a1, a2, a3, a4};
  return __builtin_bit_cast(ushort8, w);
}

// ---------------- Kernel 0: W -> Wt in PRE-SWIZZLED per-K-step tiled layout ----------
__global__ void prep_w_kernel(const float* __restrict__ Wk, const float* __restrict__ Wq,
                              const float* __restrict__ Wv, unsigned short* __restrict__ Wt) {
  int g = blockIdx.x * 256 + threadIdx.x;
  if (g >= 24 * 768) return;
  int ks = g / 768, s = g - ks * 768;
  int n = s >> 2, perm = s & 3;
  int k8 = perm ^ (n & 3) ^ ((n >> 2) & 3);
  int p = n >> 6, col = n & 63;
  const float* W = (p == 0) ? Wk : (p == 1) ? Wq : Wv;
  float sc = (p == 1) ? 0.125f * 1.44269504088896f : 1.0f;
  int kbase = ks * 32 + k8 * 8;
  ushort8 v;
#pragma unroll
  for (int e = 0; e < 8; ++e) v[e] = f32_to_bf16(W[(kbase + e) * 64 + col] * sc);
  *(ushort8*)(Wt + (size_t)g * 8) = v;
}

// ---------------- Kernel 1: projections (round-12 exact, best measured) --------------
__global__ __launch_bounds__(512) void proj_kernel(
    const float* __restrict__ x, const unsigned short* __restrict__ Wt,
    unsigned short* __restrict__ Qf, unsigned short* __restrict__ Kf,
    unsigned short* __restrict__ Vf) {
  __shared__ unsigned short Wl[2][6144];
  __shared__ unsigned short Xl[2][1024];
  const int tid = threadIdx.x;
  const int wave = tid >> 6, lane = tid & 63;
  const int lo = lane & 15, hi = lane >> 4;
  const int rg = wave & 1, ch3 = wave >> 1;
  const int row0 = blockIdx.x * 32;

  f32x4 acc[3];
#pragma unroll
  for (int t = 0; t < 3; ++t) acc[t] = (f32x4){0.f, 0.f, 0.f, 0.f};

  const int xr = (tid & 127) >> 2;
  const int xk8 = tid & 3;
  const int xslot = xr * 4 + (xk8 ^ (xr & 3) ^ ((xr >> 2) & 3));
  const float* xsrc = x + (size_t)(row0 + xr) * C_ + xk8 * 8;

  const int arow = rg * 16 + lo;
  const int aaddr = (arow * 4 + (hi ^ (arow & 3) ^ ((arow >> 2) & 3))) * 8;

  auto wstage = [&](int buf, int ks) {
    const unsigned short* base = Wt + (size_t)ks * 6144 + lane * 8;
    for (int is = wave; is < 12; is += 8)
      __builtin_amdgcn_global_load_lds((g_void*)(base + is * 512),
          (lds_void*)(&Wl[buf][is * 512]), 16, 0, 0);
  };

  float4 xa0 = {}, xa1 = {}, xb0 = {}, xb1 = {};

  wstage(0, 0);
  if (tid < 128) {
    xa0 = *(const float4*)(xsrc);
    xa1 = *(const float4*)(xsrc + 4);
  }

  for (int ks = 0; ks < 24; ++ks) {
    const int cur = ks & 1;
    asm volatile("s_waitcnt vmcnt(0)" ::: "memory");
    __syncthreads();
    if (ks + 1 < 24) {
      wstage(cur ^ 1, ks + 1);
      if (tid < 128) {
        xb0 = *(const float4*)(xsrc + (ks + 1) * 32);
        xb1 = *(const float4*)(xsrc + (ks + 1) * 32 + 4);
      }
    }
    if (tid < 128) {
      unsigned int dd[4];
      dd[0] = cvtpk_bf16(xa0.x, xa0.y);
      dd[1] = cvtpk_bf16(xa0.z, xa0.w);
      dd[2] = cvtpk_bf16(xa1.x, xa1.y);
      dd[3] = cvtpk_bf16(xa1.z, xa1.w);
      *(uint4*)(&Xl[cur][xslot * 8]) = *(uint4*)dd;
    }
    __syncthreads();
    ushort8 af = *(const ushort8*)(&Xl[cur][aaddr]);
#pragma unroll
    for (int t = 0; t < 3; ++t) {
      const int n = ch3 * 48 + t * 16 + lo;
      const int baddr = (n * 4 + (hi ^ (n & 3) ^ ((n >> 2) & 3))) * 8;
      ushort8 bfr = *(const ushort8*)(&Wl[cur][baddr]);
      acc[t] = mfma16(af, bfr, acc[t]);
    }
    xa0 = xb0; xa1 = xb1;
  }

#pragma unroll
  for (int t = 0; t < 3; ++t) {
    const int n = ch3 * 48 + t * 16 + lo;
    const int p = n >> 6, d = n & 63;
#pragma unroll
    for (int r = 0; r < 4; ++r) {
      const int rgl = row0 + rg * 16 + hi * 4 + r;
      const int b = rgl >> 11;
      const int tt = rgl & (T_ - 1);
      unsigned short val = f32_to_bf16(acc[t][r]);
      if (p == 2) {
        const size_t addr = ((((size_t)b * 128 + (tt >> 4)) * 2 + (d >> 5)) * 64 +
                             ((tt >> 3) & 1) * 32 + (d & 31)) * 8 + (tt & 7);
        Vf[addr] = val;
      } else {
        const size_t addr = ((((size_t)b * 64 + (tt >> 5)) * 4 + (d >> 4)) * 64 +
                             ((d >> 3) & 1) * 32 + (tt & 31)) * 8 + (d & 7);
        if (p == 0) Kf[addr] = val; else Qf[addr] = val;
      }
    }
  }
}

// ---------------- Kernel 2: swapped 32x32 flash attention, fragment-direct -----------
// 1D grid with XCD swizzle: b = id & 7 pins each batch to one XCD so its Q/K/V
// stays L2-resident. 2 independent waves, no LDS/barriers. Defer-max (THR=8).
__global__ __launch_bounds__(128) void attn_part_kernel(
    const unsigned short* __restrict__ Qf, const unsigned short* __restrict__ Kf,
    const unsigned short* __restrict__ Vf, unsigned short* __restrict__ Opb,
    float* __restrict__ Ml) {
  const int id = blockIdx.x;
  const int b = id & 7;
  const int r2 = id >> 3;
  const int qt = r2 & 31;
  const int ch = r2 >> 5;
  const int t0 = ch * 4;
  if (t0 > qt) return;
  const int t1 = min(qt, t0 + 3);

  const int tid = threadIdx.x;
  const int wave = tid >> 6;
  const int lane = tid & 63;
  const int il = lane & 31;
  const int h = lane >> 5;
  const int i0w = qt * 64 + wave * 32;

  const unsigned short* qbase = Qf + ((((size_t)b * 64 + (qt * 2 + wave)) * 4) << 9) + lane * 8;
  const unsigned short* kbase = Kf + (((size_t)b * 64) << 11) + lane * 8;
  const unsigned short* vbase = Vf + (((size_t)b * 128) << 10) + lane * 8;

  ushort8 qf[4];
#pragma unroll
  for (int dc = 0; dc < 4; ++dc) qf[dc] = *(const ushort8*)(qbase + (dc << 9));

  f32x16 o0 = {}, o1 = {};
  float m = -1e30f, lsum = 0.f;

  for (int jt = t0; jt <= t1; ++jt) {
    const int j0 = jt * 64;
    const size_t jg = (size_t)(jt * 2);

    ushort8 kf0[4], kf1[4];
#pragma unroll
    for (int dc = 0; dc < 4; ++dc) {
      kf0[dc] = *(const ushort8*)(kbase + (jg << 11) + (dc << 9));
      kf1[dc] = *(const ushort8*)(kbase + ((jg + 1) << 11) + (dc << 9));
    }
    ushort8 vf0[4], vf1[4];
#pragma unroll
    for (int c = 0; c < 4; ++c) {
      const size_t jc = (size_t)(jt * 4 + c);
      vf0[c] = *(const ushort8*)(vbase + (jc << 10));
      vf1[c] = *(const ushort8*)(vbase + (jc << 10) + (1 << 9));
    }

    f32x16 s0 = {}, s1 = {};
    __builtin_amdgcn_s_setprio(1);
#pragma unroll
    for (int dc = 0; dc < 4; ++dc) {
      s0 = mfma32(kf0[dc], qf[dc], s0);
      s1 = mfma32(kf1[dc], qf[dc], s1);
    }
    __builtin_amdgcn_s_setprio(0);

    if (jt == qt) {
      const int ig = i0w + il;
#pragma unroll
      for (int r = 0; r < 16; ++r) {
        const int jl = j0 + (r & 3) + 8 * (r >> 2) + 4 * h;
        if (jl > ig) s0[r] = -1e30f;
        if (jl + 32 > ig) s1[r] = -1e30f;
      }
    }

    // online softmax, tree-reduced, defer-max (THR=8)
    float mx[8];
#pragma unroll
    for (int r = 0; r < 8; ++r) mx[r] = fmaxf(fmaxf(s0[r], s0[r + 8]), fmaxf(s1[r], s1[r + 8]));
#pragma unroll
    for (int d = 4; d >= 1; d >>= 1)
#pragma unroll
      for (int r = 0; r < d; ++r) mx[r] = fmaxf(mx[r], mx[r + d]);
    float tm = fmaxf(mx[0], __shfl_xor(mx[0], 32));
    float scl = 1.0f;
    if (!__all(tm <= m + 8.0f)) {
      const float mnew = fmaxf(m, tm);
      scl = exp2f(m - mnew);
      m = mnew;
      o0 *= scl;
      o1 *= scl;
    }
    float sa = 0.f, sb = 0.f, sc2 = 0.f, sd = 0.f;
#pragma unroll
    for (int r = 0; r < 16; r += 4) {
      s0[r] = exp2f(s0[r] - m);     sa += s0[r];
      s0[r + 1] = exp2f(s0[r + 1] - m); sb += s0[r + 1];
      s0[r + 2] = exp2f(s0[r + 2] - m); sc2 += s0[r + 2];
      s0[r + 3] = exp2f(s0[r + 3] - m); sd += s0[r + 3];
    }
#pragma unroll
    for (int r = 0; r < 16; r += 4) {
      s1[r] = exp2f(s1[r] - m);     sa += s1[r];
      s1[r + 1] = exp2f(s1[r + 1] - m); sb += s1[r + 1];
      s1[r + 2] = exp2f(s1[r + 2] - m); sc2 += s1[r + 2];
      s1[r + 3] = exp2f(s1[r + 3] - m); sd += s1[r + 3];
    }
    float ts = (sa + sb) + (sc2 + sd);
    ts += __shfl_xor(ts, 32);
    lsum = lsum * scl + ts;

    __builtin_amdgcn_s_setprio(1);
#pragma unroll
    for (int c = 0; c < 4; ++c) {
      ushort8 pa = (c == 0) ? packA<0>(s0) : (c == 1) ? packA<8>(s0)
                 : (c == 2) ? packA<0>(s1) : packA<8>(s1);
      o0 = mfma32(vf0[c], pa, o0);
      o1 = mfma32(vf1[c], pa, o1);
    }
    __builtin_amdgcn_s_setprio(0);
  }

  const size_t pb = (size_t)(b * QT_ + qt) * NCH_ + ch;
  unsigned short* op = Opb + pb * 4096 + (size_t)(wave * 32 + il) * 64;
#pragma unroll
  for (int g = 0; g < 4; ++g) {
    unsigned int w0[2], w1[2];
    w0[0] = cvtpk_bf16(o0[4 * g + 0], o0[4 * g + 1]);
    w0[1] = cvtpk_bf16(o0[4 * g + 2], o0[4 * g + 3]);
    w1[0] = cvtpk_bf16(o1[4 * g + 0], o1[4 * g + 1]);
    w1[1] = cvtpk_bf16(o1[4 * g + 2], o1[4 * g + 3]);
    *(uint2*)(op + 8 * g + 4 * h) = *(uint2*)w0;
    *(uint2*)(op + 32 + 8 * g + 4 * h) = *(uint2*)w1;
  }
  if (h == 0) {
    float* ml = Ml + pb * 128;
    ml[wave * 32 + il] = m;
    ml[64 + wave * 32 + il] = lsum;
  }
}

// ---------------- Kernel 3: combine split-j partials (bf16, XCD-swizzled) ------------
__global__ __launch_bounds__(256) void attn_comb_kernel(
    const unsigned short* __restrict__ Opb, const float* __restrict__ Ml,
    float* __restrict__ out) {
  const int id = blockIdx.x;
  const int b = id & 7;
  const int qt = id >> 3;
  const int nc = (qt >> 2) + 1;
  const int row = threadIdx.x >> 2;
  const int c0 = (threadIdx.x & 3) * 16;
  const size_t pbase = (size_t)(b * QT_ + qt) * NCH_;

  float m_g = -1e30f;
  for (int c = 0; c < nc; ++c) m_g = fmaxf(m_g, Ml[(pbase + c) * 128 + row]);
  float l_g = 0.f;
  for (int c = 0; c < nc; ++c)
    l_g += Ml[(pbase + c) * 128 + 64 + row] * exp2f(Ml[(pbase + c) * 128 + row] - m_g);
  const float inv = 1.0f / l_g;

  f32x4 a0 = {0,0,0,0}, a1 = {0,0,0,0}, a2 = {0,0,0,0}, a3 = {0,0,0,0};
  for (int c = 0; c < nc; ++c) {
    const float wc = exp2f(Ml[(pbase + c) * 128 + row] - m_g);
    const unsigned short* op = Opb + (pbase + c) * 4096 + row * 64 + c0;
    ushort8 u0 = *(const ushort8*)(op);
    ushort8 u1 = *(const ushort8*)(op + 8);
    a0 += (f32x4){bf16_to_f32(u0[0]), bf16_to_f32(u0[1]), bf16_to_f32(u0[2]), bf16_to_f32(u0[3])} * wc;
    a1 += (f32x4){bf16_to_f32(u0[4]), bf16_to_f32(u0[5]), bf16_to_f32(u0[6]), bf16_to_f32(u0[7])} * wc;
    a2 += (f32x4){bf16_to_f32(u1[0]), bf16_to_f32(u1[1]), bf16_to_f32(u1[2]), bf16_to_f32(u1[3])} * wc;
    a3 += (f32x4){bf16_to_f32(u1[4]), bf16_to_f32(u1[5]), bf16_to_f32(u1[6]), bf16_to_f32(u1[7])} * wc;
  }
  float* o = out + ((size_t)b * T_ + qt * 64 + row) * 64 + c0;
  *(f32x4*)(o) = a0 * inv;
  *(f32x4*)(o + 4) = a1 * inv;
  *(f32x4*)(o + 8) = a2 * inv;
  *(f32x4*)(o + 12) = a3 * inv;
}

extern "C" void kernel_launch(void* const* d_in, const int* in_sizes, int n_in,
                              void* d_out, int out_size, void* d_ws, size_t ws_size,
                              hipStream_t stream) {
  const float* x = (const float*)d_in[0];
  const float* Wk = (const float*)d_in[1];
  const float* Wq = (const float*)d_in[2];
  const float* Wv = (const float*)d_in[3];
  float* out = (float*)d_out;

  char* ws = (char*)d_ws;
  unsigned short* Qf = (unsigned short*)(ws);                  // 2 MB  fragment-order Q
  unsigned short* Kf = (unsigned short*)(ws + (2u << 20));     // 2 MB  fragment-order K
  unsigned short* Vf = (unsigned short*)(ws + (4u << 20));     // 2 MB  fragment-order V
  unsigned short* Wt = (unsigned short*)(ws + (6u << 20));     // 288 KB swizzled
  unsigned short* Opb = (unsigned short*)(ws + (8u << 20));    // 16 MB bf16 partial O
  float* Ml = (float*)(ws + (24u << 20));                      // 1 MB  [pb][2][64] f32

  prep_w_kernel<<<dim3(72), dim3(256), 0, stream>>>(Wk, Wq, Wv, Wt);
  proj_kernel<<<dim3((B_ * T_) / 32), dim3(512), 0, stream>>>(x, Wt, Qf, Kf, Vf);
  attn_part_kernel<<<dim3(QT_ * B_ * NCH_), dim3(128), 0, stream>>>(Qf, Kf, Vf, Opb, Ml);
  attn_comb_kernel<<<dim3(QT_ * B_), dim3(256), 0, stream>>>(Opb, Ml, out);
}